// Round 8
// baseline (221.827 us; speedup 1.0000x reference)
//
#include <hip/hip_runtime.h>
#include <math.h>

#define BATCH   4096
#define N_NODES 20000
#define H       4
#define BLOCK   512
#define NW      (BLOCK / 64)

constexpr int LSTART_C[H] = {0, 100, 1100, 6100};
constexpr int LSIZE_C[H]  = {100, 1000, 5000, 13900};

__device__ __forceinline__ float waveSum(float v) {
#pragma unroll
    for (int off = 32; off > 0; off >>= 1) v += __shfl_xor(v, off);
    return v;
}
__device__ __forceinline__ float bf2f(ushort h) {
    return __uint_as_float(((unsigned)h) << 16);
}
__device__ __forceinline__ ushort f2bf_trunc(float x) {
    return (ushort)(__float_as_uint(x) >> 16);
}

// phase 1: stream y_pred(+y_true), stage bf16(e=exp(y)) to LDS, accumulate
// z=Σe, q2=Σe², dt=Σyt·e, ys=Σyt. Constant trip count + 2-deep register
// prefetch so 2 iterations of global loads are in flight per wave.
template<int L>
__device__ __forceinline__ void p1_layer(const float4* __restrict__ yp4,
                                         const float4* __restrict__ yt4,
                                         ushort* row_bf,
                                         float& z, float& q2, float& dt, float& ys,
                                         const int tid)
{
    constexpr int SQ = LSTART_C[L] / 4, NQ = LSIZE_C[L] / 4;
    constexpr int NFULL = NQ / BLOCK;
    constexpr int REM   = NQ % BLOCK;

    auto body = [&](int i, const float4& v, const float4& t) {
        float e0 = __expf(v.x), e1 = __expf(v.y), e2 = __expf(v.z), e3 = __expf(v.w);
        ushort4 h;
        h.x = f2bf_trunc(e0); h.y = f2bf_trunc(e1);
        h.z = f2bf_trunc(e2); h.w = f2bf_trunc(e3);
        *reinterpret_cast<ushort4*>(&row_bf[4 * (SQ + i)]) = h;
        z += (e0 + e1) + (e2 + e3);
        if constexpr (L > 0) {
            q2 += (e0 * e0 + e1 * e1) + (e2 * e2 + e3 * e3);
            dt += t.x * e0 + t.y * e1 + t.z * e2 + t.w * e3;
            ys += (t.x + t.y) + (t.z + t.w);
        }
    };

    if constexpr (NFULL > 0) {
        float4 v = yp4[SQ + tid];
        float4 t{};
        if constexpr (L > 0) t = yt4[SQ + tid];
#pragma unroll
        for (int k = 0; k < NFULL; ++k) {
            const int i = tid + k * BLOCK;
            float4 vn{}, tn{};
            if ((k + 1 < NFULL) || (tid < REM)) {   // k+1<NFULL folds at compile time
                vn = yp4[SQ + i + BLOCK];
                if constexpr (L > 0) tn = yt4[SQ + i + BLOCK];
            }
            body(i, v, t);
            v = vn; t = tn;
        }
        if (REM && tid < REM) body(tid + NFULL * BLOCK, v, t);
    } else {
        if (tid < REM) {
            float4 v = yp4[SQ + tid];
            float4 t{};
            if constexpr (L > 0) t = yt4[SQ + tid];
            body(tid, v, t);
        }
    }
}

// phase 2: D = Σ relu(e·invZ − e_pa·invZp). Prefetch parent-index (global)
// and child quad (LDS) one iteration ahead; LDS is read-only here.
template<int L>
__device__ __forceinline__ void p2_layer(const int4* __restrict__ pa4,
                                         const ushort* row_bf,
                                         const float invZ, const float invZp,
                                         float& D, const int tid)
{
    constexpr int S = LSTART_C[L], SQ = S / 4, NQ = LSIZE_C[L] / 4;
    constexpr int NFULL = NQ / BLOCK, REM = NQ % BLOCK;

    auto body = [&](const int4& pa, const ushort4& h) {
        float p0 = bf2f(h.x) * invZ, p1 = bf2f(h.y) * invZ;
        float p2 = bf2f(h.z) * invZ, p3 = bf2f(h.w) * invZ;
        float pp0 = bf2f(row_bf[pa.x]) * invZp, pp1 = bf2f(row_bf[pa.y]) * invZp;
        float pp2 = bf2f(row_bf[pa.z]) * invZp, pp3 = bf2f(row_bf[pa.w]) * invZp;
        D += (fmaxf(p0 - pp0, 0.f) + fmaxf(p1 - pp1, 0.f))
           + (fmaxf(p2 - pp2, 0.f) + fmaxf(p3 - pp3, 0.f));
    };

    if constexpr (NFULL > 0) {
        int4 pa = pa4[SQ + tid];
        ushort4 h = *reinterpret_cast<const ushort4*>(&row_bf[S + 4 * tid]);
#pragma unroll
        for (int k = 0; k < NFULL; ++k) {
            const int i = tid + k * BLOCK;
            int4 pan{}; ushort4 hn{};
            if ((k + 1 < NFULL) || (tid < REM)) {
                pan = pa4[SQ + i + BLOCK];
                hn  = *reinterpret_cast<const ushort4*>(&row_bf[S + 4 * (i + BLOCK)]);
            }
            body(pa, h);
            pa = pan; h = hn;
        }
        if (REM && tid < REM) body(pa, h);
    } else {
        if (tid < REM) {
            int4 pa = pa4[SQ + tid];
            ushort4 h = *reinterpret_cast<const ushort4*>(&row_bf[S + 4 * tid]);
            body(pa, h);
        }
    }
}

__global__ __launch_bounds__(BLOCK, 8) void tax_main(
    const float* __restrict__ y_pred,
    const float* __restrict__ y_true,
    const int*   __restrict__ parents,
    const float* __restrict__ alpha,
    float*       __restrict__ partial)
{
    __shared__ __align__(8) ushort row_bf[N_NODES];   // bf16(e) of the row, 40,000 B
    __shared__ float sc[NW * 13];
    __shared__ float invZ_s[H], contrib_s[H], aD_s[H];

    const int tid = threadIdx.x;
    const int b   = blockIdx.x;
    const int wid = tid >> 6;
    const int lid = tid & 63;

    const float4* yp4 = reinterpret_cast<const float4*>(y_pred + (size_t)b * N_NODES);
    const float4* yt4 = reinterpret_cast<const float4*>(y_true + (size_t)b * N_NODES);
    const int4*   pa4 = reinterpret_cast<const int4*>(parents);

    // ---- phase 1 ----
    {
        float z = 0.f, q2 = 0.f, dt = 0.f, ys = 0.f;
        p1_layer<0>(yp4, yt4, row_bf, z, q2, dt, ys, tid);
        z = waveSum(z);
        if (lid == 0) sc[wid * 13 + 0] = z;
    }
    {
        float z = 0.f, q2 = 0.f, dt = 0.f, ys = 0.f;
        p1_layer<1>(yp4, yt4, row_bf, z, q2, dt, ys, tid);
        z = waveSum(z); q2 = waveSum(q2); dt = waveSum(dt); ys = waveSum(ys);
        if (lid == 0) { float* p = &sc[wid * 13 + 1]; p[0]=z; p[1]=q2; p[2]=dt; p[3]=ys; }
    }
    {
        float z = 0.f, q2 = 0.f, dt = 0.f, ys = 0.f;
        p1_layer<2>(yp4, yt4, row_bf, z, q2, dt, ys, tid);
        z = waveSum(z); q2 = waveSum(q2); dt = waveSum(dt); ys = waveSum(ys);
        if (lid == 0) { float* p = &sc[wid * 13 + 5]; p[0]=z; p[1]=q2; p[2]=dt; p[3]=ys; }
    }
    {
        float z = 0.f, q2 = 0.f, dt = 0.f, ys = 0.f;
        p1_layer<3>(yp4, yt4, row_bf, z, q2, dt, ys, tid);
        z = waveSum(z); q2 = waveSum(q2); dt = waveSum(dt); ys = waveSum(ys);
        if (lid == 0) { float* p = &sc[wid * 13 + 9]; p[0]=z; p[1]=q2; p[2]=dt; p[3]=ys; }
    }
    __syncthreads();   // covers row_bf staging + sc

    if (tid < H) {
        const int l = tid;
        float zt = 0.f, q2t = 0.f, dtt = 0.f, yst = 0.f;
        for (int w = 0; w < NW; ++w) {
            const float* p = &sc[w * 13];
            if (l == 0) zt += p[0];
            else {
                const float* q = p + 1 + (l - 1) * 4;
                zt += q[0]; q2t += q[1]; dtt += q[2]; yst += q[3];
            }
        }
        float invZ = 1.f / zt;
        invZ_s[l] = invZ;
        float al = alpha[l];
        float S = (float)(LSIZE_C[l] + 1) + 0.5f * q2t * invZ * invZ;  // Σexp(p)≈n+1+½Σp²
        contrib_s[l] = (l > 0) ? al * (logf(S) * yst - dtt * invZ) : 0.f;
        aD_s[l] = al / (float)LSIZE_C[l];
    }
    __syncthreads();

    // ---- phase 2: LDS-only, exp-free ----
    const float iZ0 = invZ_s[0], iZ1 = invZ_s[1], iZ2 = invZ_s[2], iZ3 = invZ_s[3];
    float D1 = 0.f, D2 = 0.f, D3 = 0.f;
    p2_layer<1>(pa4, row_bf, iZ1, iZ0, D1, tid);
    p2_layer<2>(pa4, row_bf, iZ2, iZ1, D2, tid);
    p2_layer<3>(pa4, row_bf, iZ3, iZ2, D3, tid);
    D1 = waveSum(D1); D2 = waveSum(D2); D3 = waveSum(D3);
    if (lid == 0) { sc[wid * 4 + 0] = D1; sc[wid * 4 + 1] = D2; sc[wid * 4 + 2] = D3; }
    __syncthreads();

    if (tid == 0) {
        float loss = contrib_s[1] + contrib_s[2] + contrib_s[3];
        float Dl1 = 0.f, Dl2 = 0.f, Dl3 = 0.f;
        for (int w = 0; w < NW; ++w) {
            Dl1 += sc[w * 4 + 0]; Dl2 += sc[w * 4 + 1]; Dl3 += sc[w * 4 + 2];
        }
        loss += aD_s[1] * Dl1 + aD_s[2] * Dl2 + aD_s[3] * Dl3;
        partial[b] = loss;
    }
}

__global__ __launch_bounds__(1024) void tax_reduce(
    const float* __restrict__ partial, float* __restrict__ out)
{
    __shared__ float red[16];
    const int tid = threadIdx.x, wid = tid >> 6, lid = tid & 63;
    float v = 0.f;
    for (int i = tid; i < BATCH; i += 1024) v += partial[i];
    v = waveSum(v);
    if (lid == 0) red[wid] = v;
    __syncthreads();
    if (wid == 0) {
        float x = (lid < 16) ? red[lid] : 0.f;
        x = waveSum(x);
        if (lid == 0) out[0] = x * (1.0f / (float)BATCH);
    }
}

extern "C" void kernel_launch(void* const* d_in, const int* in_sizes, int n_in,
                              void* d_out, int out_size, void* d_ws, size_t ws_size,
                              hipStream_t stream) {
    const float* y_pred  = (const float*)d_in[0];
    const float* y_true  = (const float*)d_in[1];
    const int*   parents = (const int*)d_in[2];
    const float* alpha   = (const float*)d_in[3];
    float* partial = (float*)d_ws;           // BATCH floats = 16 KB scratch
    float* out     = (float*)d_out;

    tax_main<<<dim3(BATCH), dim3(BLOCK), 0, stream>>>(y_pred, y_true, parents, alpha, partial);
    tax_reduce<<<dim3(1), dim3(1024), 0, stream>>>(partial, out);
}

// Round 9
// 177.735 us; speedup vs baseline: 1.2481x; 1.2481x over previous
//
#include <hip/hip_runtime.h>
#include <math.h>

#define BATCH   4096
#define N_NODES 20000
#define H       4
#define BLOCK   1024
#define NPW     12               // producer waves (0..11)
#define PTHR    (NPW * 64)       // 768 producer threads
#define CTHR    (BLOCK - PTHR)   // 256 consumer threads (waves 12..15)
#define ROWS    8
#define GRID    (BATCH / ROWS)   // 512 blocks = 2/CU, exactly resident

constexpr int LSTART_C[H] = {0, 100, 1100, 6100};
constexpr int LSIZE_C[H]  = {100, 1000, 5000, 13900};

__device__ __forceinline__ float waveSum(float v) {
#pragma unroll
    for (int off = 32; off > 0; off >>= 1) v += __shfl_xor(v, off);
    return v;
}
__device__ __forceinline__ float bf2f(ushort h) {
    return __uint_as_float(((unsigned)h) << 16);
}
__device__ __forceinline__ ushort f2bf_trunc(float x) {
    return (ushort)(__float_as_uint(x) >> 16);
}

// phase 1 (R6-style dynamic loop, no prefetch): e=exp(y) staged as bf16,
// accumulate z=Σe, q2=Σe², dt=Σyt·e, ys=Σyt
template<int L, int STRIDE>
__device__ __forceinline__ void p1_layer(const float4* __restrict__ yp4,
                                         const float4* __restrict__ yt4,
                                         ushort* row_bf,
                                         float& z, float& q2, float& dt, float& ys,
                                         const int t)
{
    const int SQ = LSTART_C[L] / 4, NQ = LSIZE_C[L] / 4;
    for (int i = t; i < NQ; i += STRIDE) {
        float4 v = yp4[SQ + i];
        float e0 = __expf(v.x), e1 = __expf(v.y), e2 = __expf(v.z), e3 = __expf(v.w);
        ushort4 h;
        h.x = f2bf_trunc(e0); h.y = f2bf_trunc(e1);
        h.z = f2bf_trunc(e2); h.w = f2bf_trunc(e3);
        *reinterpret_cast<ushort4*>(&row_bf[4 * (SQ + i)]) = h;
        z += (e0 + e1) + (e2 + e3);
        if constexpr (L > 0) {
            q2 += (e0 * e0 + e1 * e1) + (e2 * e2 + e3 * e3);
            float4 tt = yt4[SQ + i];
            dt += tt.x * e0 + tt.y * e1 + tt.z * e2 + tt.w * e3;
            ys += (tt.x + tt.y) + (tt.z + tt.w);
        }
    }
}

// phase 2: D = Σ relu(e·invZ − e_pa·invZp), read-only on LDS
template<int L, int STRIDE>
__device__ __forceinline__ void p2_layer(const int4* __restrict__ pa4,
                                         const ushort* row_bf,
                                         const float invZ, const float invZp,
                                         float& D, const int t)
{
    const int S = LSTART_C[L], SQ = S / 4, NQ = LSIZE_C[L] / 4;
    for (int i = t; i < NQ; i += STRIDE) {
        ushort4 h = *reinterpret_cast<const ushort4*>(&row_bf[S + 4 * i]);
        int4 pa = pa4[SQ + i];
        float p0 = bf2f(h.x) * invZ, p1 = bf2f(h.y) * invZ;
        float p2 = bf2f(h.z) * invZ, p3 = bf2f(h.w) * invZ;
        float pp0 = bf2f(row_bf[pa.x]) * invZp, pp1 = bf2f(row_bf[pa.y]) * invZp;
        float pp2 = bf2f(row_bf[pa.z]) * invZp, pp3 = bf2f(row_bf[pa.w]) * invZp;
        D += (fmaxf(p0 - pp0, 0.f) + fmaxf(p1 - pp1, 0.f))
           + (fmaxf(p2 - pp2, 0.f) + fmaxf(p3 - pp3, 0.f));
    }
}

__global__ __launch_bounds__(BLOCK, 8) void tax_main(
    const float* __restrict__ y_pred,
    const float* __restrict__ y_true,
    const int*   __restrict__ parents,
    const float* __restrict__ alpha,
    float*       __restrict__ partial)
{
    __shared__ __align__(16) ushort buf[2][N_NODES];   // 80,000 B: double row buffer
    __shared__ float pz[2][NPW * 13];                  // producer partials, by parity
    __shared__ float Dpart[2][4][3];                   // consumer D partials, by parity
    __shared__ float cce_save[2];                      // cce part of a row, by parity

    const int tid = threadIdx.x;
    const int wid = tid >> 6;
    const int lid = tid & 63;
    const int r0  = blockIdx.x * ROWS;
    const int4* pa4 = reinterpret_cast<const int4*>(parents);

    // ---- producer: phase 1 of `row` into buf[par]/pz[par] (waves 0..11) ----
    auto produce = [&](int row, int par) {
        const float4* yp4 = reinterpret_cast<const float4*>(y_pred + (size_t)row * N_NODES);
        const float4* yt4 = reinterpret_cast<const float4*>(y_true + (size_t)row * N_NODES);
        ushort* rb = buf[par];
        float*  PZ = pz[par];
        {
            float z = 0.f, q2 = 0.f, dt = 0.f, ys = 0.f;
            p1_layer<0, PTHR>(yp4, yt4, rb, z, q2, dt, ys, tid);
            z = waveSum(z);
            if (lid == 0) PZ[wid * 13 + 0] = z;
        }
        {
            float z = 0.f, q2 = 0.f, dt = 0.f, ys = 0.f;
            p1_layer<1, PTHR>(yp4, yt4, rb, z, q2, dt, ys, tid);
            z = waveSum(z); q2 = waveSum(q2); dt = waveSum(dt); ys = waveSum(ys);
            if (lid == 0) { float* p = &PZ[wid * 13 + 1]; p[0]=z; p[1]=q2; p[2]=dt; p[3]=ys; }
        }
        {
            float z = 0.f, q2 = 0.f, dt = 0.f, ys = 0.f;
            p1_layer<2, PTHR>(yp4, yt4, rb, z, q2, dt, ys, tid);
            z = waveSum(z); q2 = waveSum(q2); dt = waveSum(dt); ys = waveSum(ys);
            if (lid == 0) { float* p = &PZ[wid * 13 + 5]; p[0]=z; p[1]=q2; p[2]=dt; p[3]=ys; }
        }
        {
            float z = 0.f, q2 = 0.f, dt = 0.f, ys = 0.f;
            p1_layer<3, PTHR>(yp4, yt4, rb, z, q2, dt, ys, tid);
            z = waveSum(z); q2 = waveSum(q2); dt = waveSum(dt); ys = waveSum(ys);
            if (lid == 0) { float* p = &PZ[wid * 13 + 9]; p[0]=z; p[1]=q2; p[2]=dt; p[3]=ys; }
        }
    };

    // ---- consumer: phase 2 of `row` staged at parity `par` (waves 12..15) ----
    auto consume = [&](int row, int par) {
        const float* P = pz[par];
        float z0 = 0.f, z1 = 0.f, z2 = 0.f, z3 = 0.f;
        for (int w = 0; w < NPW; ++w) {          // broadcast LDS reads (conflict-free)
            z0 += P[w * 13 + 0]; z1 += P[w * 13 + 1];
            z2 += P[w * 13 + 5]; z3 += P[w * 13 + 9];
        }
        const float iZ0 = 1.f / z0, iZ1 = 1.f / z1, iZ2 = 1.f / z2, iZ3 = 1.f / z3;
        const ushort* rb = buf[par];
        const int ct = tid - PTHR;
        float D1 = 0.f, D2 = 0.f, D3 = 0.f;
        p2_layer<1, CTHR>(pa4, rb, iZ1, iZ0, D1, ct);
        p2_layer<2, CTHR>(pa4, rb, iZ2, iZ1, D2, ct);
        p2_layer<3, CTHR>(pa4, rb, iZ3, iZ2, D3, ct);
        D1 = waveSum(D1); D2 = waveSum(D2); D3 = waveSum(D3);
        const int cw = wid - NPW;
        if (lid == 0) { Dpart[par][cw][0] = D1; Dpart[par][cw][1] = D2; Dpart[par][cw][2] = D3; }
        if (tid == PTHR) {     // cce part of this row (one lane, hidden under others' phase 2)
            float c = 0.f;
#pragma unroll
            for (int l = 1; l < H; ++l) {
                float zz = 0.f, qq = 0.f, dd = 0.f, yy = 0.f;
                for (int w = 0; w < NPW; ++w) {
                    const float* q = &P[w * 13 + 1 + (l - 1) * 4];
                    zz += q[0]; qq += q[1]; dd += q[2]; yy += q[3];
                }
                float iz = 1.f / zz;
                float S = (float)(LSIZE_C[l] + 1) + 0.5f * qq * iz * iz;  // Σexp(p)≈n+1+½Σp²
                c += alpha[l] * (logf(S) * yy - dd * iz);
            }
            cce_save[par] = c;
        }
    };

    auto writePartial = [&](int row, int par) {   // loss of `row` from Dpart/cce_save[par]
        float d1 = 0.f, d2 = 0.f, d3 = 0.f;
        for (int w = 0; w < 4; ++w) {
            d1 += Dpart[par][w][0]; d2 += Dpart[par][w][1]; d3 += Dpart[par][w][2];
        }
        partial[row] = cce_save[par]
                     + alpha[1] * d1 / (float)LSIZE_C[1]
                     + alpha[2] * d2 / (float)LSIZE_C[2]
                     + alpha[3] * d3 / (float)LSIZE_C[3];
    };

    // ---- head: stage row 0 (consumers idle this round) ----
    if (wid < NPW) produce(r0, 0);
    __syncthreads();

    // ---- steady state: produce(row k) || consume(row k-1); retire row k-2 ----
#pragma unroll 1
    for (int k = 1; k < ROWS; ++k) {
        const int par = k & 1;
        if (wid < NPW) {
            produce(r0 + k, par);
        } else {
            if (tid == PTHR && k >= 2) writePartial(r0 + k - 2, par);  // row k-2 parity == par
            consume(r0 + k - 1, par ^ 1);
        }
        __syncthreads();
    }

    // ---- tail: retire row ROWS-2; all 16 waves run phase 2 of last row ----
    {
        const int parL = (ROWS - 1) & 1;
        if (tid == PTHR) writePartial(r0 + ROWS - 2, (ROWS - 2) & 1);

        const float* P = pz[parL];
        float z0 = 0.f, z1 = 0.f, z2 = 0.f, z3 = 0.f;
        for (int w = 0; w < NPW; ++w) {
            z0 += P[w * 13 + 0]; z1 += P[w * 13 + 1];
            z2 += P[w * 13 + 5]; z3 += P[w * 13 + 9];
        }
        const float iZ0 = 1.f / z0, iZ1 = 1.f / z1, iZ2 = 1.f / z2, iZ3 = 1.f / z3;
        const ushort* rb = buf[parL];
        float D1 = 0.f, D2 = 0.f, D3 = 0.f;
        p2_layer<1, BLOCK>(pa4, rb, iZ1, iZ0, D1, tid);
        p2_layer<2, BLOCK>(pa4, rb, iZ2, iZ1, D2, tid);
        p2_layer<3, BLOCK>(pa4, rb, iZ3, iZ2, D3, tid);
        D1 = waveSum(D1); D2 = waveSum(D2); D3 = waveSum(D3);
        float* Dtail = &pz[0][0];          // pz[0] is dead at the tail; reuse (48 floats)
        if (lid == 0) { Dtail[wid * 3 + 0] = D1; Dtail[wid * 3 + 1] = D2; Dtail[wid * 3 + 2] = D3; }
        __syncthreads();

        if (tid == 0) {
            float c = 0.f;
#pragma unroll
            for (int l = 1; l < H; ++l) {
                float zz = 0.f, qq = 0.f, dd = 0.f, yy = 0.f;
                for (int w = 0; w < NPW; ++w) {
                    const float* q = &P[w * 13 + 1 + (l - 1) * 4];
                    zz += q[0]; qq += q[1]; dd += q[2]; yy += q[3];
                }
                float iz = 1.f / zz;
                float S = (float)(LSIZE_C[l] + 1) + 0.5f * qq * iz * iz;
                c += alpha[l] * (logf(S) * yy - dd * iz);
            }
            float d1 = 0.f, d2 = 0.f, d3 = 0.f;
            for (int w = 0; w < 16; ++w) {
                d1 += Dtail[w * 3 + 0]; d2 += Dtail[w * 3 + 1]; d3 += Dtail[w * 3 + 2];
            }
            partial[r0 + ROWS - 1] = c
                + alpha[1] * d1 / (float)LSIZE_C[1]
                + alpha[2] * d2 / (float)LSIZE_C[2]
                + alpha[3] * d3 / (float)LSIZE_C[3];
        }
    }
}

__global__ __launch_bounds__(1024) void tax_reduce(
    const float* __restrict__ partial, float* __restrict__ out)
{
    __shared__ float red[16];
    const int tid = threadIdx.x, wid = tid >> 6, lid = tid & 63;
    float v = 0.f;
    for (int i = tid; i < BATCH; i += 1024) v += partial[i];
    v = waveSum(v);
    if (lid == 0) red[wid] = v;
    __syncthreads();
    if (wid == 0) {
        float x = (lid < 16) ? red[lid] : 0.f;
        x = waveSum(x);
        if (lid == 0) out[0] = x * (1.0f / (float)BATCH);
    }
}

extern "C" void kernel_launch(void* const* d_in, const int* in_sizes, int n_in,
                              void* d_out, int out_size, void* d_ws, size_t ws_size,
                              hipStream_t stream) {
    const float* y_pred  = (const float*)d_in[0];
    const float* y_true  = (const float*)d_in[1];
    const int*   parents = (const int*)d_in[2];
    const float* alpha   = (const float*)d_in[3];
    float* partial = (float*)d_ws;           // BATCH floats = 16 KB scratch
    float* out     = (float*)d_out;

    tax_main<<<dim3(GRID), dim3(BLOCK), 0, stream>>>(y_pred, y_true, parents, alpha, partial);
    tax_reduce<<<dim3(1), dim3(1024), 0, stream>>>(partial, out);
}

// Round 10
// 125.073 us; speedup vs baseline: 1.7736x; 1.4210x over previous
//
#include <hip/hip_runtime.h>
#include <math.h>

#define BATCH   4096
#define N_NODES 20000
#define H       4
#define BLOCK   512
#define NW      (BLOCK / 64)

constexpr int LSTART_C[H] = {0, 100, 1100, 6100};
constexpr int LSIZE_C[H]  = {100, 1000, 5000, 13900};

__device__ __forceinline__ float waveSum(float v) {
#pragma unroll
    for (int off = 32; off > 0; off >>= 1) v += __shfl_xor(v, off);
    return v;
}
__device__ __forceinline__ float bf2f(ushort h) {
    return __uint_as_float(((unsigned)h) << 16);
}
__device__ __forceinline__ ushort f2bf_trunc(float x) {
    return (ushort)(__float_as_uint(x) >> 16);
}

// phase 1: e=exp(y) staged as bf16; accumulate z=Σe, q2=Σe², dt=Σyt·e, ys=Σyt.
// Unroll-2: issue BOTH independent global loads before either body so two
// memory ops are in flight per wave (MLP=2), no cross-iteration rotation.
template<int L>
__device__ __forceinline__ void p1_layer(const float4* __restrict__ yp4,
                                         const float4* __restrict__ yt4,
                                         ushort* row_bf,
                                         float& z, float& q2, float& dt, float& ys,
                                         const int tid)
{
    constexpr int SQ = LSTART_C[L] / 4, NQ = LSIZE_C[L] / 4;

    auto body = [&](int i, const float4& v, const float4& t) {
        float e0 = __expf(v.x), e1 = __expf(v.y), e2 = __expf(v.z), e3 = __expf(v.w);
        ushort4 h;
        h.x = f2bf_trunc(e0); h.y = f2bf_trunc(e1);
        h.z = f2bf_trunc(e2); h.w = f2bf_trunc(e3);
        *reinterpret_cast<ushort4*>(&row_bf[4 * (SQ + i)]) = h;
        z += (e0 + e1) + (e2 + e3);
        if constexpr (L > 0) {
            q2 += (e0 * e0 + e1 * e1) + (e2 * e2 + e3 * e3);
            dt += t.x * e0 + t.y * e1 + t.z * e2 + t.w * e3;
            ys += (t.x + t.y) + (t.z + t.w);
        }
    };

    int i = tid;
    for (; i + BLOCK < NQ; i += 2 * BLOCK) {
        float4 va = yp4[SQ + i];
        float4 vb = yp4[SQ + i + BLOCK];
        float4 ta{}, tb{};
        if constexpr (L > 0) { ta = yt4[SQ + i]; tb = yt4[SQ + i + BLOCK]; }
        body(i, va, ta);
        body(i + BLOCK, vb, tb);
    }
    if (i < NQ) {
        float4 v = yp4[SQ + i];
        float4 t{};
        if constexpr (L > 0) t = yt4[SQ + i];
        body(i, v, t);
    }
}

// phase 2: D = Σ relu(e·invZ − e_pa·invZp); unroll-2 on the pa4 global loads
// and LDS child reads so two gather chains are in flight per wave.
template<int L>
__device__ __forceinline__ void p2_layer(const int4* __restrict__ pa4,
                                         const ushort* row_bf,
                                         const float invZ, const float invZp,
                                         float& D, const int tid)
{
    constexpr int S = LSTART_C[L], SQ = S / 4, NQ = LSIZE_C[L] / 4;

    auto body = [&](const int4& pa, const ushort4& h) {
        float p0 = bf2f(h.x) * invZ, p1 = bf2f(h.y) * invZ;
        float p2 = bf2f(h.z) * invZ, p3 = bf2f(h.w) * invZ;
        float pp0 = bf2f(row_bf[pa.x]) * invZp, pp1 = bf2f(row_bf[pa.y]) * invZp;
        float pp2 = bf2f(row_bf[pa.z]) * invZp, pp3 = bf2f(row_bf[pa.w]) * invZp;
        D += (fmaxf(p0 - pp0, 0.f) + fmaxf(p1 - pp1, 0.f))
           + (fmaxf(p2 - pp2, 0.f) + fmaxf(p3 - pp3, 0.f));
    };

    int i = tid;
    for (; i + BLOCK < NQ; i += 2 * BLOCK) {
        int4 paa = pa4[SQ + i];
        int4 pab = pa4[SQ + i + BLOCK];
        ushort4 ha = *reinterpret_cast<const ushort4*>(&row_bf[S + 4 * i]);
        ushort4 hb = *reinterpret_cast<const ushort4*>(&row_bf[S + 4 * (i + BLOCK)]);
        body(paa, ha);
        body(pab, hb);
    }
    if (i < NQ) {
        int4 pa = pa4[SQ + i];
        ushort4 h = *reinterpret_cast<const ushort4*>(&row_bf[S + 4 * i]);
        body(pa, h);
    }
}

__global__ __launch_bounds__(BLOCK, 8) void tax_main(
    const float* __restrict__ y_pred,
    const float* __restrict__ y_true,
    const int*   __restrict__ parents,
    const float* __restrict__ alpha,
    float*       __restrict__ partial)
{
    __shared__ __align__(8) ushort row_bf[N_NODES];   // bf16(e) of the row, 40,000 B
    __shared__ float sc[NW * 13];
    __shared__ float invZ_s[H], contrib_s[H], aD_s[H];

    const int tid = threadIdx.x;
    const int b   = blockIdx.x;
    const int wid = tid >> 6;
    const int lid = tid & 63;

    const float4* yp4 = reinterpret_cast<const float4*>(y_pred + (size_t)b * N_NODES);
    const float4* yt4 = reinterpret_cast<const float4*>(y_true + (size_t)b * N_NODES);
    const int4*   pa4 = reinterpret_cast<const int4*>(parents);

    // ---- phase 1 ----
    {
        float z = 0.f, q2 = 0.f, dt = 0.f, ys = 0.f;
        p1_layer<0>(yp4, yt4, row_bf, z, q2, dt, ys, tid);
        z = waveSum(z);
        if (lid == 0) sc[wid * 13 + 0] = z;
    }
    {
        float z = 0.f, q2 = 0.f, dt = 0.f, ys = 0.f;
        p1_layer<1>(yp4, yt4, row_bf, z, q2, dt, ys, tid);
        z = waveSum(z); q2 = waveSum(q2); dt = waveSum(dt); ys = waveSum(ys);
        if (lid == 0) { float* p = &sc[wid * 13 + 1]; p[0]=z; p[1]=q2; p[2]=dt; p[3]=ys; }
    }
    {
        float z = 0.f, q2 = 0.f, dt = 0.f, ys = 0.f;
        p1_layer<2>(yp4, yt4, row_bf, z, q2, dt, ys, tid);
        z = waveSum(z); q2 = waveSum(q2); dt = waveSum(dt); ys = waveSum(ys);
        if (lid == 0) { float* p = &sc[wid * 13 + 5]; p[0]=z; p[1]=q2; p[2]=dt; p[3]=ys; }
    }
    {
        float z = 0.f, q2 = 0.f, dt = 0.f, ys = 0.f;
        p1_layer<3>(yp4, yt4, row_bf, z, q2, dt, ys, tid);
        z = waveSum(z); q2 = waveSum(q2); dt = waveSum(dt); ys = waveSum(ys);
        if (lid == 0) { float* p = &sc[wid * 13 + 9]; p[0]=z; p[1]=q2; p[2]=dt; p[3]=ys; }
    }
    __syncthreads();   // covers row_bf staging + sc

    if (tid < H) {
        const int l = tid;
        float zt = 0.f, q2t = 0.f, dtt = 0.f, yst = 0.f;
        for (int w = 0; w < NW; ++w) {
            const float* p = &sc[w * 13];
            if (l == 0) zt += p[0];
            else {
                const float* q = p + 1 + (l - 1) * 4;
                zt += q[0]; q2t += q[1]; dtt += q[2]; yst += q[3];
            }
        }
        float invZ = 1.f / zt;
        invZ_s[l] = invZ;
        float al = alpha[l];
        float S = (float)(LSIZE_C[l] + 1) + 0.5f * q2t * invZ * invZ;  // Σexp(p)≈n+1+½Σp²
        contrib_s[l] = (l > 0) ? al * (logf(S) * yst - dtt * invZ) : 0.f;
        aD_s[l] = al / (float)LSIZE_C[l];
    }
    __syncthreads();

    // ---- phase 2: LDS-only, exp-free ----
    const float iZ0 = invZ_s[0], iZ1 = invZ_s[1], iZ2 = invZ_s[2], iZ3 = invZ_s[3];
    float D1 = 0.f, D2 = 0.f, D3 = 0.f;
    p2_layer<1>(pa4, row_bf, iZ1, iZ0, D1, tid);
    p2_layer<2>(pa4, row_bf, iZ2, iZ1, D2, tid);
    p2_layer<3>(pa4, row_bf, iZ3, iZ2, D3, tid);
    D1 = waveSum(D1); D2 = waveSum(D2); D3 = waveSum(D3);
    if (lid == 0) { sc[wid * 4 + 0] = D1; sc[wid * 4 + 1] = D2; sc[wid * 4 + 2] = D3; }
    __syncthreads();

    if (tid == 0) {
        float loss = contrib_s[1] + contrib_s[2] + contrib_s[3];
        float Dl1 = 0.f, Dl2 = 0.f, Dl3 = 0.f;
        for (int w = 0; w < NW; ++w) {
            Dl1 += sc[w * 4 + 0]; Dl2 += sc[w * 4 + 1]; Dl3 += sc[w * 4 + 2];
        }
        loss += aD_s[1] * Dl1 + aD_s[2] * Dl2 + aD_s[3] * Dl3;
        partial[b] = loss;
    }
}

__global__ __launch_bounds__(1024) void tax_reduce(
    const float* __restrict__ partial, float* __restrict__ out)
{
    __shared__ float red[16];
    const int tid = threadIdx.x, wid = tid >> 6, lid = tid & 63;
    float v = 0.f;
    for (int i = tid; i < BATCH; i += 1024) v += partial[i];
    v = waveSum(v);
    if (lid == 0) red[wid] = v;
    __syncthreads();
    if (wid == 0) {
        float x = (lid < 16) ? red[lid] : 0.f;
        x = waveSum(x);
        if (lid == 0) out[0] = x * (1.0f / (float)BATCH);
    }
}

extern "C" void kernel_launch(void* const* d_in, const int* in_sizes, int n_in,
                              void* d_out, int out_size, void* d_ws, size_t ws_size,
                              hipStream_t stream) {
    const float* y_pred  = (const float*)d_in[0];
    const float* y_true  = (const float*)d_in[1];
    const int*   parents = (const int*)d_in[2];
    const float* alpha   = (const float*)d_in[3];
    float* partial = (float*)d_ws;           // BATCH floats = 16 KB scratch
    float* out     = (float*)d_out;

    tax_main<<<dim3(BATCH), dim3(BLOCK), 0, stream>>>(y_pred, y_true, parents, alpha, partial);
    tax_reduce<<<dim3(1), dim3(1024), 0, stream>>>(partial, out);
}